// Round 9
// baseline (162.680 us; speedup 1.0000x reference)
//
#include <hip/hip_runtime.h>
#include <hip/hip_bf16.h>
#include <math.h>

#define BB 2
#define HH 16
#define LL 1024
#define DD 64
#define EE 1024
#define NEGV -1e20f

typedef __attribute__((ext_vector_type(8))) short bf16x8;
typedef __attribute__((ext_vector_type(4))) float f32x4;

__device__ __forceinline__ float bf2f(__hip_bfloat16 x){ return __bfloat162float(x); }
__device__ __forceinline__ float gelu_erf(float x){
    return 0.5f * x * (1.0f + erff(x * 0.70710678118654752f));
}
// VALU-only gelu(x)*(1/32) for the score path -- NO TRANS ops (R8, confirmed:
// kD dropped below the 44us fill floor).
__device__ __forceinline__ float gelu32_poly(float x){
    float t = fminf(fmaxf(x, -3.2f), 3.2f);
    float t2 = t * t;
    float u = fmaf(t2, fmaf(t2, 0.0024694f, -0.046578f), 0.38541f);
    float phi = fmaf(t, u, 0.5f);
    phi = fminf(fmaxf(phi, 0.f), 1.f);
    return x * phi * 0.03125f;
}
// VALU-only exp for the k-loop (R9): argument x = gelu(s)/32 is in
// [-0.0054, ~9] (gelu min -0.17; un-normalized additive softmax), so no
// overflow/underflow handling needed. n = rndne(x*log2e) [VALU], r = x-n*ln2
// (|r|<=0.347), degree-5 Horner (rel err ~2e-6 << bf16 2^-9), scale via
// exponent-bit stuffing. Removes the last 8 TRANS per lane-tile: the k-loop
// is now TRANS-free.
__device__ __forceinline__ float exp_valu(float x){
    float nf = rintf(x * 1.44269504f);          // v_rndne_f32 (VALU)
    float r  = fmaf(nf, -0.69314718056f, x);    // |r| <= 0.3466
    float p  = fmaf(r, 0.008333333f, 0.041666668f);
    p = fmaf(r, p, 0.16666667f);
    p = fmaf(r, p, 0.5f);
    p = fmaf(r, p, 1.0f);
    p = fmaf(r, p, 1.0f);
    int ni = (int)nf;                           // exact (nf is integral)
    float sc = __int_as_float((ni + 127) << 23);
    return p * sc;
}
__device__ __forceinline__ float ldx(const void* p, size_t i, int f32){
    return f32 ? ((const float*)p)[i] : bf2f(((const __hip_bfloat16*)p)[i]);
}
__device__ __forceinline__ short f2bs(float x){
    __hip_bfloat16 h = __float2bfloat16(x);
    return *(short*)&h;
}
__device__ __forceinline__ float bs2f(unsigned short u){
    return __uint_as_float(((unsigned)u) << 16);
}
__device__ __forceinline__ unsigned int pk2(float lo, float hi){
    unsigned int a = (unsigned short)f2bs(lo);
    unsigned int b = (unsigned short)f2bs(hi);
    return (b << 16) | a;
}
__device__ __forceinline__ bf16x8 ld8b(const void* p, size_t i, int f32){
    bf16x8 r;
    if (f32){
        const float4* f = (const float4*)((const float*)p + i);
        float4 a = f[0], b = f[1];
        r[0]=f2bs(a.x); r[1]=f2bs(a.y); r[2]=f2bs(a.z); r[3]=f2bs(a.w);
        r[4]=f2bs(b.x); r[5]=f2bs(b.y); r[6]=f2bs(b.z); r[7]=f2bs(b.w);
    } else {
        r = *(const bf16x8*)((const __hip_bfloat16*)p + i);
    }
    return r;
}
__device__ __forceinline__ float redsum16(float x){
    x += __shfl_xor(x, 1); x += __shfl_xor(x, 2);
    x += __shfl_xor(x, 4); x += __shfl_xor(x, 8);
    return x;
}
// detect f32 (1) vs bf16 (0): wave-parallel, 1 load/lane + ballot
__device__ __forceinline__ int detect_f32_wave(const unsigned int* p, int lane){
    unsigned int e0 = (p[lane] >> 7) & 0xFFu;
    int inband = (e0 >= 0x60u && e0 <= 0x8Eu) ? 1 : 0;
    unsigned long long m = __ballot(inband);
    return (__popcll(m) >= 48) ? 0 : 1;
}
// ber_mask storage encoding: 0=u8, 1=i32, 2=bf16, 3=f32 -- wave-parallel,
// 2 bytes/lane over the first 128 bytes
__device__ __forceinline__ int ber_code_wave(const unsigned char* r, int lane){
    int j0 = lane * 2, j1 = lane * 2 + 1;
    unsigned char c0 = r[j0], c1 = r[j1];
    int big = (c0 > 1) || (c1 > 1);
    int odd = (((j1 & 3) == 1) && c1) || (((j0 & 3) == 1) && c0);
    int nz  = (((j0 & 3) != 0) && c0) || (((j1 & 3) != 0) && c1);
    unsigned long long mb = __ballot(big);
    unsigned long long mo = __ballot(odd);
    unsigned long long mn = __ballot(nz);
    if (mb) return mo ? 2 : 3;
    return mn ? 0 : 1;
}
__device__ __forceinline__ float ber_val(const unsigned char* r, int i, int code){
    switch (code){
        case 0:  return r[i] ? 1.f : 0.f;
        case 1:  return (((const int*)r)[i] != 0) ? 1.f : 0.f;
        case 2:  return (((const unsigned short*)r)[i] != 0) ? 1.f : 0.f;
        default: return (((const float*)r)[i] != 0.f) ? 1.f : 0.f;
    }
}

// ---------------------------------------------------------------------------
// kA: 3 independent roles, one launch:
//  blk<512:        depthwise conv+bias+residual -> qbf (PRE-BN bf16) + BN
//                  partial sums; blk 0 publishes dtype flag.
//  512<=blk<1024:  key-softmax partial denoms (max-free) + berf decode.
//  blk>=1024:      MFMA value projection -> vbT[bh][e][l].
// ---------------------------------------------------------------------------
__global__ __launch_bounds__(256, 2) void kA(const void* __restrict__ query,
                                             const void* __restrict__ conv_w,
                                             const void* __restrict__ conv_b,
                                             const void* __restrict__ keys,
                                             const void* __restrict__ values,
                                             const void* __restrict__ w_v,
                                             const unsigned char* __restrict__ ber_raw,
                                             float* __restrict__ statsP,
                                             float* __restrict__ Sp,
                                             float* __restrict__ berf,
                                             int* __restrict__ wsflag,
                                             __hip_bfloat16* __restrict__ qbf,
                                             __hip_bfloat16* __restrict__ vbT){
    __shared__ float tile[66][67];
    __shared__ float r1[256], r2[256];
    __shared__ float ss[4][64];
    int blk = blockIdx.x, t = threadIdx.x;
    int lane = t & 63;
    if (blk < 512){
        // ---------------- conv role ----------------
        const int f32 = detect_f32_wave((const unsigned int*)query, lane);
        if (blk == 0 && t == 0) wsflag[0] = f32;
        int lt = blk & 15, h = (blk >> 4) & 15, b = blk >> 8;
        int bh = b * HH + h;
        int l0 = lt * 64;
        if (t < 66){ tile[t][0] = 0.f; tile[t][65] = 0.f; }
        __syncthreads();
        // vectorized staging: float4 (f32) / uint4=8bf16 (bf16) global loads
        if (f32){
            const float* qp = (const float*)query;
            for (int i = t; i < 66 * 16; i += 256){
                int r = i >> 4, d0 = (i & 15) * 4;
                int l = l0 - 1 + r;
                float4 v = (l >= 0 && l < LL)
                    ? *(const float4*)(qp + ((size_t)b * LL + l) * EE + h * 64 + d0)
                    : (float4){0.f, 0.f, 0.f, 0.f};
                tile[r][d0 + 1] = v.x; tile[r][d0 + 2] = v.y;
                tile[r][d0 + 3] = v.z; tile[r][d0 + 4] = v.w;
            }
        } else {
            const __hip_bfloat16* qp = (const __hip_bfloat16*)query;
            for (int i = t; i < 66 * 8; i += 256){
                int r = i >> 3, d0 = (i & 7) * 8;
                int l = l0 - 1 + r;
                if (l >= 0 && l < LL){
                    uint4 v = *(const uint4*)(qp + ((size_t)b * LL + l) * EE + h * 64 + d0);
                    unsigned short* s = (unsigned short*)&v;
                    #pragma unroll
                    for (int j = 0; j < 8; ++j) tile[r][d0 + 1 + j] = bs2f(s[j]);
                } else {
                    #pragma unroll
                    for (int j = 0; j < 8; ++j) tile[r][d0 + 1 + j] = 0.f;
                }
            }
        }
        __syncthreads();
        float w9[9];
        #pragma unroll
        for (int i = 0; i < 9; ++i) w9[i] = ldx(conv_w, h * 9 + i, f32);
        float cb = ldx(conv_b, h, f32);
        int l = t & 63, db = t >> 6, d0 = db * 16;
        float s1 = 0.f, s2 = 0.f;
        unsigned short ob[16];
        #pragma unroll
        for (int jj = 0; jj < 16; ++jj){
            int d = d0 + jj;
            float acc = cb + tile[l + 1][d + 1];
            #pragma unroll
            for (int di = 0; di < 3; ++di)
                #pragma unroll
                for (int dj = 0; dj < 3; ++dj)
                    acc += w9[di * 3 + dj] * tile[l + di][d + dj];
            s1 += acc; s2 += acc * acc;
            ob[jj] = (unsigned short)f2bs(acc);
        }
        __hip_bfloat16* orow = qbf + ((size_t)bh * LL + l0 + l) * DD + d0;
        #pragma unroll
        for (int g = 0; g < 4; ++g){
            ushort4 u; u.x = ob[g*4]; u.y = ob[g*4+1]; u.z = ob[g*4+2]; u.w = ob[g*4+3];
            *(ushort4*)(orow + g * 4) = u;
        }
        r1[t] = s1; r2[t] = s2;
        __syncthreads();
        for (int s = 128; s > 0; s >>= 1){
            if (t < s){ r1[t] += r1[t + s]; r2[t] += r2[t + s]; }
            __syncthreads();
        }
        if (t == 0){
            statsP[h * 32 + b * 16 + lt] = r1[0];
            statsP[512 + h * 32 + b * 16 + lt] = r2[0];
        }
    } else if (blk < 1024){
        // ---------------- key-softmax role ----------------
        int blk2 = blk - 512;
        const int f32 = detect_f32_wave((const unsigned int*)keys, lane);
        const int code = ber_code_wave(ber_raw, lane);
        int ch = blk2 & 15, h = (blk2 >> 4) & 15, b = blk2 >> 8;
        int ex = t & 63, ly = t >> 6;
        int e = h * 64 + ex;
        float s = 0.f;
        #pragma unroll 4
        for (int l = ch * 64 + ly; l < ch * 64 + 64; l += 4){
            float keep = ber_val(ber_raw, b * LL + l, code);
            float x = (keep != 0.f) ? ldx(keys, ((size_t)b * LL + l) * EE + e, f32) : NEGV;
            s += __expf(x);
        }
        ss[ly][ex] = s;
        __syncthreads();
        if (ly == 0)
            Sp[(b * 16 + ch) * EE + e] = ss[0][ex] + ss[1][ex] + ss[2][ex] + ss[3][ex];
        if (h == 0 && t < 64)
            berf[b * LL + ch * 64 + t] = ber_val(ber_raw, b * LL + ch * 64 + t, code);
    } else {
        // ---------------- MFMA v-projection role ----------------
        const int f32 = detect_f32_wave((const unsigned int*)values, lane);
        int blk2 = blk - 1024;
        int lt = blk2 & 15, bh = blk2 >> 4;
        int h = bh & 15, b = bh >> 4;
        int w = t >> 6;
        int lid = lane & 15, quad = lane >> 4;
        int l = lt * 64 + w * 16 + lid;
        bf16x8 av[2];
        #pragma unroll
        for (int ck = 0; ck < 2; ++ck)
            av[ck] = ld8b(values, ((size_t)b * LL + l) * EE + h * 64 + ck * 32 + quad * 8, f32);
        f32x4 Dv[4];
        #pragma unroll
        for (int et = 0; et < 4; ++et){
            Dv[et] = (f32x4){0.f, 0.f, 0.f, 0.f};
            #pragma unroll
            for (int ck = 0; ck < 2; ++ck){
                bf16x8 bw = ld8b(w_v, (size_t)(et * 16 + lid) * 64 + ck * 32 + quad * 8, f32);
                Dv[et] = __builtin_amdgcn_mfma_f32_16x16x32_bf16(av[ck], bw, Dv[et], 0, 0, 0);
            }
        }
        #pragma unroll
        for (int et = 0; et < 4; ++et){
            ushort4 u;
            u.x = (unsigned short)f2bs(Dv[et][0]);
            u.y = (unsigned short)f2bs(Dv[et][1]);
            u.z = (unsigned short)f2bs(Dv[et][2]);
            u.w = (unsigned short)f2bs(Dv[et][3]);
            *(ushort4*)(vbT + ((size_t)bh * DD + et * 16 + lid) * LL + lt * 64 + w * 16 + quad * 4) = u;
        }
    }
}

// ---------------------------------------------------------------------------
// kB: elementwise build pass. Per block (h uniform): derive BN coef from
// statsP (32-lane shuffle reduce), then
//  - q path: qbf <- bf16(gelu_erf(BN(qbf))) in place,
//  - keys path: kb = bf16(gelu(exp(keys)*Sinv)) with bernoulli mask.
// 1024 blocks x 256 thr, 8+8 elements/thread.
// ---------------------------------------------------------------------------
__global__ __launch_bounds__(256, 2) void kB(const void* __restrict__ keys,
                                             const void* __restrict__ bn_g,
                                             const void* __restrict__ bn_b,
                                             const float* __restrict__ statsP,
                                             const float* __restrict__ Sp,
                                             const float* __restrict__ berf,
                                             const int* __restrict__ wsflag,
                                             __hip_bfloat16* __restrict__ kb,
                                             __hip_bfloat16* __restrict__ qbf){
    __shared__ float sinv_s[64];
    __shared__ float coefs[2];
    int blk = blockIdx.x, t = threadIdx.x;
    const int f32 = wsflag[0];
    int i8 = (blk * 256 + t) * 8;       // [b][h][l][d] over kb/qbf (2M els)
    int d0 = i8 & 63, l = (i8 >> 6) & 1023, h = (i8 >> 16) & 15, b = i8 >> 20;
    // per-block BN coef for this h (h uniform across the block)
    if (t < 32){
        float v1 = statsP[h * 32 + t];
        float v2 = statsP[512 + h * 32 + t];
        #pragma unroll
        for (int off = 1; off < 32; off <<= 1){
            v1 += __shfl_xor(v1, off);
            v2 += __shfl_xor(v2, off);
        }
        if (t == 0){
            const float N = (float)(BB * LL * DD);
            float mean = v1 / N;
            float var  = fmaxf(v2 / N - mean * mean, 0.f);
            float a = ldx(bn_g, h, f32) * rsqrtf(var + 1e-5f);
            coefs[0] = a;
            coefs[1] = ldx(bn_b, h, f32) - mean * a;
        }
    }
    if (t < 64){
        int e = h * 64 + t;
        float S = 0.f;
        #pragma unroll
        for (int ch = 0; ch < 16; ++ch) S += Sp[(b * 16 + ch) * EE + e];
        sinv_s[t] = 1.f / S;
    }
    __syncthreads();
    const float bna = coefs[0], bnc = coefs[1];
    // ---- q path: BN + GELU in place on qbf
    {
        uint4 qr = *(const uint4*)(qbf + i8);
        unsigned short* qs = (unsigned short*)&qr;
        uint4 qw;
        unsigned short* qws = (unsigned short*)&qw;
        #pragma unroll
        for (int j = 0; j < 8; ++j){
            float x = bs2f(qs[j]) * bna + bnc;
            qws[j] = (unsigned short)f2bs(gelu_erf(x));
        }
        *(uint4*)(qbf + i8) = qw;
    }
    // ---- keys path
    size_t kbase = ((size_t)b * LL + l) * EE + h * 64 + d0;
    float kv[8];
    if (f32){
        const float4* kp = (const float4*)((const float*)keys + kbase);
        float4 a = kp[0], c = kp[1];
        kv[0]=a.x; kv[1]=a.y; kv[2]=a.z; kv[3]=a.w;
        kv[4]=c.x; kv[5]=c.y; kv[6]=c.z; kv[7]=c.w;
    } else {
        uint4 kr = *(const uint4*)((const __hip_bfloat16*)keys + kbase);
        unsigned short* ks = (unsigned short*)&kr;
        #pragma unroll
        for (int j = 0; j < 8; ++j) kv[j] = bs2f(ks[j]);
    }
    float keep = berf[b * LL + l];
    uint4 kw;
    unsigned short* kws = (unsigned short*)&kw;
    #pragma unroll
    for (int j = 0; j < 8; ++j){
        float km = (keep != 0.f) ? kv[j] : NEGV;
        float p = __expf(km) * sinv_s[d0 + j];
        kws[j] = (unsigned short)f2bs(gelu_erf(p));
    }
    *(uint4*)(kb + i8) = kw;
}

// ---------------------------------------------------------------------------
// kD: barrier-free MFMA flash attention, register-only P path, rotated K
// prefetch (R5 base, best measured). R9 changes:
//  (1) softmax exp -> exp_valu (VALU-only; argument range [-0.0054,~9] is
//      overflow-free). Combined with R8's poly-gelu the k-loop is TRANS-free.
//  (2) early V prefetch: loadV(kt+1) issues into a separate vn[] right after
//      the K reissue (BEFORE softmax), vf<-vn rotates after PV. V's hiding
//      distance grows from ~200cy (S+softmax) to ~500cy (+PV+pack). +16 VGPR
//      (~100 total, under the (128,4) cap). Single non-unrolled loop, static
//      indexing (R6's x2-unroll double-buffer caused scratch; this must keep
//      WRITE_SIZE at 8.2MB -- growth means spill, revert).
// S^T = mfma(K,Q) with permuted K-row addressing makes the packed softmax
// output directly the PV A-fragment. Q arrives pre-BN+GELU'd from kB.
// 2048 blocks x 128 thr; 16 q-rows/block, waves split k 32/32; un-normalized
// additive softmax (LN over d is scale-invariant).
// ---------------------------------------------------------------------------
__global__ __launch_bounds__(128, 4) void kD(const __hip_bfloat16* __restrict__ qbf,
                                             const __hip_bfloat16* __restrict__ kb,
                                             const __hip_bfloat16* __restrict__ vbT,
                                             const void* __restrict__ w_o,
                                             const void* __restrict__ b_o,
                                             const void* __restrict__ ln_g,
                                             const void* __restrict__ ln_b,
                                             const int* __restrict__ wsflag,
                                             void* __restrict__ out){
    __shared__ __align__(16) float Ol[16][68];              // wave-1 O for combine
    __shared__ __align__(16) __hip_bfloat16 onb[16][72];    // LN'd rows (A-frags)
    int blk = blockIdx.x;
    int qt = 63 - (blk >> 5);         // 16-row q tile; LPT (heavy first)
    int bh = blk & 31;                // b*16+h ; same-bh blocks share an XCD
    int h = bh & 15, b = bh >> 4;
    int t = threadIdx.x;
    int w = t >> 6, lane = t & 63;
    int lid = lane & 15, quad = lane >> 4;
    const int f32o = wsflag[0];

    // Q frags: already BN+GELU'd bf16 (kB) -- direct vector loads
    int qrow = qt * 16 + lid;
    bf16x8 qf[2];
    #pragma unroll
    for (int ck = 0; ck < 2; ++ck)
        qf[ck] = *(const bf16x8*)(qbf + ((size_t)bh * LL + qrow) * DD + ck * 32 + quad * 8);

    const __hip_bfloat16* kbb = kb + (size_t)bh * LL * DD;
    const __hip_bfloat16* vbb = vbT + (size_t)bh * DD * LL;
    f32x4 O[4];
    #pragma unroll
    for (int nt = 0; nt < 4; ++nt) O[nt] = (f32x4){0.f, 0.f, 0.f, 0.f};
    const int qlane = qt * 16 + quad * 4;      // + r = this lane's OUTPUT q rows
    const int qcol  = qt * 16 + lid;           // this lane's q for S^T/P values
    const int nkt = (qt >> 2) + 1;             // 64-k tiles covering causal range

    bf16x8 kf[4], vf[4], vn[4];
    // permuted K-row load: A-row lid of chunk nt2 gets K-row
    // (lid>>2)*8 + nt2*4 + (lid&3)  (makes S^T C-layout == PV A-frag layout)
    auto loadK = [&](int kw){
        #pragma unroll
        for (int nt2 = 0; nt2 < 2; ++nt2)
            #pragma unroll
            for (int ck = 0; ck < 2; ++ck)
                kf[nt2 * 2 + ck] = *(const bf16x8*)(kbb
                    + (size_t)(kw + (lid >> 2) * 8 + nt2 * 4 + (lid & 3)) * DD
                    + ck * 32 + quad * 8);
    };
    auto loadVf = [&](int kw){
        #pragma unroll
        for (int nt = 0; nt < 4; ++nt)
            vf[nt] = *(const bf16x8*)(vbb + (size_t)(nt * 16 + lid) * LL + kw + quad * 8);
    };
    auto loadVn = [&](int kw){
        #pragma unroll
        for (int nt = 0; nt < 4; ++nt)
            vn[nt] = *(const bf16x8*)(vbb + (size_t)(nt * 16 + lid) * LL + kw + quad * 8);
    };

    loadK(w * 32);
    loadVf(w * 32);

    for (int kt0 = 0; kt0 < nkt; ++kt0){
        int kw0 = kt0 * 64 + w * 32;
        const bool more = (kt0 + 1 < nkt);
        // S^T = K Q^T for this wave's 32k x 16q (2 x 16k chunks); consumes kf
        f32x4 S[2];
        __builtin_amdgcn_s_setprio(1);
        #pragma unroll
        for (int nt2 = 0; nt2 < 2; ++nt2){
            S[nt2] = (f32x4){0.f, 0.f, 0.f, 0.f};
            #pragma unroll
            for (int ck = 0; ck < 2; ++ck)
                S[nt2] = __builtin_amdgcn_mfma_f32_16x16x32_bf16(kf[nt2 * 2 + ck], qf[ck], S[nt2], 0, 0, 0);
        }
        __builtin_amdgcn_s_setprio(0);
        // rotate K prefetch into the same regs (WAR after S consumed), and
        // issue next V into vn NOW -- softmax + PV hide both
        if (more){
            loadK((kt0 + 1) * 64 + w * 32);
            loadVn((kt0 + 1) * 64 + w * 32);
        }
        // p = exp(poly_gelu(s)) causal-masked, packed to PV A-frag:
        // lane holds k = kw0 + quad*8 + nt2*4 + r, q = qcol. TRANS-free.
        unsigned int pw0, pw1, pw2, pw3;
        {
            float ps[8];
            #pragma unroll
            for (int nt2 = 0; nt2 < 2; ++nt2)
                #pragma unroll
                for (int r = 0; r < 4; ++r){
                    int k = kw0 + quad * 8 + nt2 * 4 + r;
                    float x = gelu32_poly(S[nt2][r]);
                    float p = exp_valu(x);
                    ps[nt2 * 4 + r] = (k <= qcol) ? p : 0.f;
                }
            pw0 = pk2(ps[0], ps[1]); pw1 = pk2(ps[2], ps[3]);
            pw2 = pk2(ps[4], ps[5]); pw3 = pk2(ps[6], ps[7]);
        }
        union { unsigned int u[4]; bf16x8 v; } pu;
        pu.u[0] = pw0; pu.u[1] = pw1; pu.u[2] = pw2; pu.u[3] = pw3;
        bf16x8 pa = pu.v;
        // O += P V ; consumes vf
        __builtin_amdgcn_s_setprio(1);
        #pragma unroll
        for (int nt = 0; nt < 4; ++nt)
            O[nt] = __builtin_amdgcn_mfma_f32_16x16x32_bf16(pa, vf[nt], O[nt], 0, 0, 0);
        __builtin_amdgcn_s_setprio(0);
        // rotate V buffer (vn was issued pre-softmax; copy is 16 v_mov)
        if (more){
            #pragma unroll
            for (int nt = 0; nt < 4; ++nt) vf[nt] = vn[nt];
        }
    }

    // ---- combine the two k-half accumulators
    if (w == 1){
        #pragma unroll
        for (int nt = 0; nt < 4; ++nt)
            #pragma unroll
            for (int r = 0; r < 4; ++r)
                Ol[quad * 4 + r][nt * 16 + lid] = O[nt][r];
    }
    __syncthreads();
    if (w == 0){
        #pragma unroll
        for (int nt = 0; nt < 4; ++nt)
            #pragma unroll
            for (int r = 0; r < 4; ++r)
                O[nt][r] += Ol[quad * 4 + r][nt * 16 + lid];
        // LayerNorm over d (scale-invariant: unnormalized O is fine)
        float lng_v[4], lnb_v[4];
        #pragma unroll
        for (int nt = 0; nt < 4; ++nt){
            lng_v[nt] = ldx(ln_g, nt * 16 + lid, f32o);
            lnb_v[nt] = ldx(ln_b, nt * 16 + lid, f32o);
        }
        #pragma unroll
        for (int r = 0; r < 4; ++r){
            float s = O[0][r] + O[1][r] + O[2][r] + O[3][r];
            s = redsum16(s);
            float mu = s * (1.f / 64.f);
            float vs = 0.f;
            #pragma unroll
            for (int nt = 0; nt < 4; ++nt){ float d2 = O[nt][r] - mu; vs += d2 * d2; }
            vs = redsum16(vs);
            float iv = rsqrtf(vs * (1.f / 64.f) + 1e-5f);
            #pragma unroll
            for (int nt = 0; nt < 4; ++nt){
                float on = (O[nt][r] - mu) * iv * lng_v[nt] + lnb_v[nt];
                onb[quad * 4 + r][nt * 16 + lid] = __float2bfloat16(on);
            }
        }
    }
    __syncthreads();
    // ---- W_o epilogue, e-tiles split across waves (et = w*2 + i)
    bf16x8 oa0 = *(const bf16x8*)&onb[lid][quad * 8];
    bf16x8 oa1 = *(const bf16x8*)&onb[lid][32 + quad * 8];
    #pragma unroll
    for (int i = 0; i < 2; ++i){
        int et = w * 2 + i;
        float bo = ldx(b_o, et * 16 + lid, f32o);
        f32x4 R = (f32x4){bo, bo, bo, bo};
        bf16x8 bw0 = ld8b(w_o, (size_t)(et * 16 + lid) * 64 + quad * 8, f32o);
        bf16x8 bw1 = ld8b(w_o, (size_t)(et * 16 + lid) * 64 + 32 + quad * 8, f32o);
        R = __builtin_amdgcn_mfma_f32_16x16x32_bf16(oa0, bw0, R, 0, 0, 0);
        R = __builtin_amdgcn_mfma_f32_16x16x32_bf16(oa1, bw1, R, 0, 0, 0);
        #pragma unroll
        for (int r = 0; r < 4; ++r){
            size_t oidx = ((size_t)b * LL + qlane + r) * EE + h * 64 + et * 16 + lid;
            if (f32o) ((float*)out)[oidx] = R[r];
            else      ((__hip_bfloat16*)out)[oidx] = __float2bfloat16(R[r]);
        }
    }
}

// ---------------------------------------------------------------------------
extern "C" void kernel_launch(void* const* d_in, const int* in_sizes, int n_in,
                              void* d_out, int out_size, void* d_ws, size_t ws_size,
                              hipStream_t stream){
    int iq=-1, ik=-1, iv=-1, iber=-1, icw=-1, icb=-1, ibg=-1, ibb=-1,
        iwv=-1, ilg=-1, ilb=-1, iwo=-1, ibo=-1;
    int nbig=0, n16=0, n4096=0, n64=0;
    for (int i = 0; i < n_in; ++i){
        int s = in_sizes[i];
        if (s == BB*LL*EE){ if (nbig==0) iq=i; else if (nbig==1) ik=i; else if (nbig==2) iv=i; nbig++; }
        else if (s == BB*LL) iber = i;
        else if (s == HH*9)  icw = i;
        else if (s == HH){ if (n16==0) icb=i; else if (n16==1) ibg=i; else ibb=i; n16++; }
        else if (s == DD*DD){ if (n4096==0) iwv=i; else iwo=i; n4096++; }
        else if (s == DD){ if (n64==0) ilg=i; else if (n64==1) ilb=i; else ibo=i; n64++; }
    }
    if (iq<0||ik<0||iv<0||iber<0||icw<0||icb<0||ibg<0||ibb<0||iwv<0||ilg<0||ilb<0||iwo<0||ibo<0){
        iq=0; ik=1; iv=2; iber=5; icw=6; icb=7; ibg=8; ibb=9; iwv=10; ilg=11; ilb=12; iwo=13; ibo=14;
    }

    const size_t NEL = (size_t)BB * HH * LL * DD;   // 2M
    __hip_bfloat16* qbf = (__hip_bfloat16*)d_ws;    // 4 MB (conv out; kB applies BN+GELU in place)
    __hip_bfloat16* kbw = qbf + NEL;                // 4 MB
    __hip_bfloat16* vbT = kbw + NEL;                // 4 MB
    float* f     = (float*)(vbT + NEL);
    float* berf  = f;              // 2048
    float* statsP= f + 2048;       // 1024
    float* Sp    = f + 3072;       // 32768
    int*   wsflag= (int*)(f + 35840);  // 4

    hipLaunchKernelGGL(kA, dim3(1536), dim3(256), 0, stream,
                       d_in[iq], d_in[icw], d_in[icb], d_in[ik], d_in[iv], d_in[iwv],
                       (const unsigned char*)d_in[iber], statsP, Sp, berf, wsflag,
                       qbf, vbT);
    hipLaunchKernelGGL(kB, dim3(1024), dim3(256), 0, stream,
                       d_in[ik], d_in[ibg], d_in[ibb], statsP, Sp, berf, wsflag,
                       kbw, qbf);
    hipLaunchKernelGGL(kD, dim3(2048), dim3(128), 0, stream,
                       qbf, kbw, vbT, d_in[iwo], d_in[ibo], d_in[ilg], d_in[ilb],
                       wsflag, d_out);
}

// Round 10
// 147.489 us; speedup vs baseline: 1.1030x; 1.1030x over previous
//
#include <hip/hip_runtime.h>
#include <hip/hip_bf16.h>
#include <math.h>

#define BB 2
#define HH 16
#define LL 1024
#define DD 64
#define EE 1024
#define NEGV -1e20f

typedef __attribute__((ext_vector_type(8))) short bf16x8;
typedef __attribute__((ext_vector_type(4))) float f32x4;

__device__ __forceinline__ float bf2f(__hip_bfloat16 x){ return __bfloat162float(x); }
__device__ __forceinline__ float gelu_erf(float x){
    return 0.5f * x * (1.0f + erff(x * 0.70710678118654752f));
}
// VALU-only gelu(x)*(1/32) for the score path -- NO TRANS ops (R8).
__device__ __forceinline__ float gelu32_poly(float x){
    float t = fminf(fmaxf(x, -3.2f), 3.2f);
    float t2 = t * t;
    float u = fmaf(t2, fmaf(t2, 0.0024694f, -0.046578f), 0.38541f);
    float phi = fmaf(t, u, 0.5f);
    phi = fminf(fmaxf(phi, 0.f), 1.f);
    return x * phi * 0.03125f;
}
// VALU-only exp (R9): argument in [-0.0054,~9], overflow-free.
__device__ __forceinline__ float exp_valu(float x){
    float nf = rintf(x * 1.44269504f);
    float r  = fmaf(nf, -0.69314718056f, x);
    float p  = fmaf(r, 0.008333333f, 0.041666668f);
    p = fmaf(r, p, 0.16666667f);
    p = fmaf(r, p, 0.5f);
    p = fmaf(r, p, 1.0f);
    p = fmaf(r, p, 1.0f);
    int ni = (int)nf;
    float sc = __int_as_float((ni + 127) << 23);
    return p * sc;
}
__device__ __forceinline__ float ldx(const void* p, size_t i, int f32){
    return f32 ? ((const float*)p)[i] : bf2f(((const __hip_bfloat16*)p)[i]);
}
__device__ __forceinline__ short f2bs(float x){
    __hip_bfloat16 h = __float2bfloat16(x);
    return *(short*)&h;
}
__device__ __forceinline__ float bs2f(unsigned short u){
    return __uint_as_float(((unsigned)u) << 16);
}
__device__ __forceinline__ unsigned int pk2(float lo, float hi){
    unsigned int a = (unsigned short)f2bs(lo);
    unsigned int b = (unsigned short)f2bs(hi);
    return (b << 16) | a;
}
__device__ __forceinline__ bf16x8 ld8b(const void* p, size_t i, int f32){
    bf16x8 r;
    if (f32){
        const float4* f = (const float4*)((const float*)p + i);
        float4 a = f[0], b = f[1];
        r[0]=f2bs(a.x); r[1]=f2bs(a.y); r[2]=f2bs(a.z); r[3]=f2bs(a.w);
        r[4]=f2bs(b.x); r[5]=f2bs(b.y); r[6]=f2bs(b.z); r[7]=f2bs(b.w);
    } else {
        r = *(const bf16x8*)((const __hip_bfloat16*)p + i);
    }
    return r;
}
__device__ __forceinline__ float redsum16(float x){
    x += __shfl_xor(x, 1); x += __shfl_xor(x, 2);
    x += __shfl_xor(x, 4); x += __shfl_xor(x, 8);
    return x;
}
// detect f32 (1) vs bf16 (0): wave-parallel, 1 load/lane + ballot
__device__ __forceinline__ int detect_f32_wave(const unsigned int* p, int lane){
    unsigned int e0 = (p[lane] >> 7) & 0xFFu;
    int inband = (e0 >= 0x60u && e0 <= 0x8Eu) ? 1 : 0;
    unsigned long long m = __ballot(inband);
    return (__popcll(m) >= 48) ? 0 : 1;
}
// ber_mask storage encoding: 0=u8, 1=i32, 2=bf16, 3=f32 -- wave-parallel
__device__ __forceinline__ int ber_code_wave(const unsigned char* r, int lane){
    int j0 = lane * 2, j1 = lane * 2 + 1;
    unsigned char c0 = r[j0], c1 = r[j1];
    int big = (c0 > 1) || (c1 > 1);
    int odd = (((j1 & 3) == 1) && c1) || (((j0 & 3) == 1) && c0);
    int nz  = (((j0 & 3) != 0) && c0) || (((j1 & 3) != 0) && c1);
    unsigned long long mb = __ballot(big);
    unsigned long long mo = __ballot(odd);
    unsigned long long mn = __ballot(nz);
    if (mb) return mo ? 2 : 3;
    return mn ? 0 : 1;
}
__device__ __forceinline__ float ber_val(const unsigned char* r, int i, int code){
    switch (code){
        case 0:  return r[i] ? 1.f : 0.f;
        case 1:  return (((const int*)r)[i] != 0) ? 1.f : 0.f;
        case 2:  return (((const unsigned short*)r)[i] != 0) ? 1.f : 0.f;
        default: return (((const float*)r)[i] != 0.f) ? 1.f : 0.f;
    }
}

// ---------------------------------------------------------------------------
// Tiled K/V layouts for kD (R10): every k-loop load instruction reads ONE
// CONTIGUOUS 1KB block (64 lanes x 16B). Previously each instruction was a
// 16-row scatter (64B segments at 128B-2KB strides) -- 16 memory-pipe
// segments/instr x 8 instr/tile queued at L1/TA is the prime suspect for the
// 43-46us kD floor that survived 6 schedule variants (R3-R9 all null).
//   kb2 idx: ((bh*32 + (krow>>5))*4 + nt2*2+ck)*512 + lane*8 + e
//     where rr=krow&31, lid=((rr>>3)<<2)|(rr&3), nt2=(rr>>2)&1,
//           ck=d>>5, quad=(d>>3)&3, lane=quad*16+lid, e=d&7
//   vb2 idx: ((bh*32 + (l>>5))*4 + nt)*512 + lane*8 + e
//     where nt=d>>4, lid=d&15, quad=(l>>3)&3, lane=quad*16+lid, e=l&7
// Producers (kB, kAv) write scattered (fire-and-forget); consumers coalesce.
// ---------------------------------------------------------------------------

// ---------------------------------------------------------------------------
// kA: 3 independent roles, one launch:
//  blk<512:        depthwise conv+bias+residual -> qbf (PRE-BN bf16) + BN
//                  partial sums; blk 0 publishes dtype flag.
//  512<=blk<1024:  key-softmax partial denoms (max-free) + berf decode.
//  blk>=1024:      MFMA value projection -> vb2 (tiled layout).
// ---------------------------------------------------------------------------
__global__ __launch_bounds__(256, 2) void kA(const void* __restrict__ query,
                                             const void* __restrict__ conv_w,
                                             const void* __restrict__ conv_b,
                                             const void* __restrict__ keys,
                                             const void* __restrict__ values,
                                             const void* __restrict__ w_v,
                                             const unsigned char* __restrict__ ber_raw,
                                             float* __restrict__ statsP,
                                             float* __restrict__ Sp,
                                             float* __restrict__ berf,
                                             int* __restrict__ wsflag,
                                             __hip_bfloat16* __restrict__ qbf,
                                             __hip_bfloat16* __restrict__ vb2){
    __shared__ float tile[66][67];
    __shared__ float r1[256], r2[256];
    __shared__ float ss[4][64];
    int blk = blockIdx.x, t = threadIdx.x;
    int lane = t & 63;
    if (blk < 512){
        // ---------------- conv role ----------------
        const int f32 = detect_f32_wave((const unsigned int*)query, lane);
        if (blk == 0 && t == 0) wsflag[0] = f32;
        int lt = blk & 15, h = (blk >> 4) & 15, b = blk >> 8;
        int bh = b * HH + h;
        int l0 = lt * 64;
        if (t < 66){ tile[t][0] = 0.f; tile[t][65] = 0.f; }
        __syncthreads();
        if (f32){
            const float* qp = (const float*)query;
            for (int i = t; i < 66 * 16; i += 256){
                int r = i >> 4, d0 = (i & 15) * 4;
                int l = l0 - 1 + r;
                float4 v = (l >= 0 && l < LL)
                    ? *(const float4*)(qp + ((size_t)b * LL + l) * EE + h * 64 + d0)
                    : (float4){0.f, 0.f, 0.f, 0.f};
                tile[r][d0 + 1] = v.x; tile[r][d0 + 2] = v.y;
                tile[r][d0 + 3] = v.z; tile[r][d0 + 4] = v.w;
            }
        } else {
            const __hip_bfloat16* qp = (const __hip_bfloat16*)query;
            for (int i = t; i < 66 * 8; i += 256){
                int r = i >> 3, d0 = (i & 7) * 8;
                int l = l0 - 1 + r;
                if (l >= 0 && l < LL){
                    uint4 v = *(const uint4*)(qp + ((size_t)b * LL + l) * EE + h * 64 + d0);
                    unsigned short* s = (unsigned short*)&v;
                    #pragma unroll
                    for (int j = 0; j < 8; ++j) tile[r][d0 + 1 + j] = bs2f(s[j]);
                } else {
                    #pragma unroll
                    for (int j = 0; j < 8; ++j) tile[r][d0 + 1 + j] = 0.f;
                }
            }
        }
        __syncthreads();
        float w9[9];
        #pragma unroll
        for (int i = 0; i < 9; ++i) w9[i] = ldx(conv_w, h * 9 + i, f32);
        float cb = ldx(conv_b, h, f32);
        int l = t & 63, db = t >> 6, d0 = db * 16;
        float s1 = 0.f, s2 = 0.f;
        unsigned short ob[16];
        #pragma unroll
        for (int jj = 0; jj < 16; ++jj){
            int d = d0 + jj;
            float acc = cb + tile[l + 1][d + 1];
            #pragma unroll
            for (int di = 0; di < 3; ++di)
                #pragma unroll
                for (int dj = 0; dj < 3; ++dj)
                    acc += w9[di * 3 + dj] * tile[l + di][d + dj];
            s1 += acc; s2 += acc * acc;
            ob[jj] = (unsigned short)f2bs(acc);
        }
        __hip_bfloat16* orow = qbf + ((size_t)bh * LL + l0 + l) * DD + d0;
        #pragma unroll
        for (int g = 0; g < 4; ++g){
            ushort4 u; u.x = ob[g*4]; u.y = ob[g*4+1]; u.z = ob[g*4+2]; u.w = ob[g*4+3];
            *(ushort4*)(orow + g * 4) = u;
        }
        r1[t] = s1; r2[t] = s2;
        __syncthreads();
        for (int s = 128; s > 0; s >>= 1){
            if (t < s){ r1[t] += r1[t + s]; r2[t] += r2[t + s]; }
            __syncthreads();
        }
        if (t == 0){
            statsP[h * 32 + b * 16 + lt] = r1[0];
            statsP[512 + h * 32 + b * 16 + lt] = r2[0];
        }
    } else if (blk < 1024){
        // ---------------- key-softmax role ----------------
        int blk2 = blk - 512;
        const int f32 = detect_f32_wave((const unsigned int*)keys, lane);
        const int code = ber_code_wave(ber_raw, lane);
        int ch = blk2 & 15, h = (blk2 >> 4) & 15, b = blk2 >> 8;
        int ex = t & 63, ly = t >> 6;
        int e = h * 64 + ex;
        float s = 0.f;
        #pragma unroll 4
        for (int l = ch * 64 + ly; l < ch * 64 + 64; l += 4){
            float keep = ber_val(ber_raw, b * LL + l, code);
            float x = (keep != 0.f) ? ldx(keys, ((size_t)b * LL + l) * EE + e, f32) : NEGV;
            s += __expf(x);
        }
        ss[ly][ex] = s;
        __syncthreads();
        if (ly == 0)
            Sp[(b * 16 + ch) * EE + e] = ss[0][ex] + ss[1][ex] + ss[2][ex] + ss[3][ex];
        if (h == 0 && t < 64)
            berf[b * LL + ch * 64 + t] = ber_val(ber_raw, b * LL + ch * 64 + t, code);
    } else {
        // ---------------- MFMA v-projection role -> vb2 tiled ----------------
        const int f32 = detect_f32_wave((const unsigned int*)values, lane);
        int blk2 = blk - 1024;
        int lt = blk2 & 15, bh = blk2 >> 4;
        int h = bh & 15, b = bh >> 4;
        int w = t >> 6;
        int lid = lane & 15, quad = lane >> 4;
        int l = lt * 64 + w * 16 + lid;
        bf16x8 av[2];
        #pragma unroll
        for (int ck = 0; ck < 2; ++ck)
            av[ck] = ld8b(values, ((size_t)b * LL + l) * EE + h * 64 + ck * 32 + quad * 8, f32);
        f32x4 Dv[4];
        #pragma unroll
        for (int et = 0; et < 4; ++et){
            Dv[et] = (f32x4){0.f, 0.f, 0.f, 0.f};
            #pragma unroll
            for (int ck = 0; ck < 2; ++ck){
                bf16x8 bw = ld8b(w_v, (size_t)(et * 16 + lid) * 64 + ck * 32 + quad * 8, f32);
                Dv[et] = __builtin_amdgcn_mfma_f32_16x16x32_bf16(av[ck], bw, Dv[et], 0, 0, 0);
            }
        }
        // store into vb2 tiled layout: element (d=et*16+lid, lo=lt*64+w*16+quad*4+j)
        // kt32 = lo>>5 = lt*2 + (w>>1); within-tile lv = (w&1)*16 + quad*4 + j
        // quadV = lv>>3 (constant over j), e = lv&7 = (quad&1)*4 + j
        int kt32 = lt * 2 + (w >> 1);
        int lv0 = (w & 1) * 16 + quad * 4;
        int quadV = lv0 >> 3;
        #pragma unroll
        for (int et = 0; et < 4; ++et){
            ushort4 u;
            u.x = (unsigned short)f2bs(Dv[et][0]);
            u.y = (unsigned short)f2bs(Dv[et][1]);
            u.z = (unsigned short)f2bs(Dv[et][2]);
            u.w = (unsigned short)f2bs(Dv[et][3]);
            size_t dst = ((size_t)(bh * 32 + kt32) * 4 + et) * 512
                       + (quadV * 16 + lid) * 8 + (lv0 & 7);
            *(ushort4*)(vb2 + dst) = u;
        }
    }
}

// ---------------------------------------------------------------------------
// kB: elementwise build pass. Per block (h uniform): derive BN coef from
// statsP (32-lane shuffle reduce), then
//  - q path: qbf <- bf16(gelu_erf(BN(qbf))) in place,
//  - keys path: kb2 (TILED layout) = bf16(gelu(exp(keys)*Sinv)) with mask.
// 1024 blocks x 256 thr, 8+8 elements/thread.
// ---------------------------------------------------------------------------
__global__ __launch_bounds__(256, 2) void kB(const void* __restrict__ keys,
                                             const void* __restrict__ bn_g,
                                             const void* __restrict__ bn_b,
                                             const float* __restrict__ statsP,
                                             const float* __restrict__ Sp,
                                             const float* __restrict__ berf,
                                             const int* __restrict__ wsflag,
                                             __hip_bfloat16* __restrict__ kb2,
                                             __hip_bfloat16* __restrict__ qbf){
    __shared__ float sinv_s[64];
    __shared__ float coefs[2];
    int blk = blockIdx.x, t = threadIdx.x;
    const int f32 = wsflag[0];
    int i8 = (blk * 256 + t) * 8;       // [b][h][l][d] over qbf (2M els)
    int d0 = i8 & 63, l = (i8 >> 6) & 1023, h = (i8 >> 16) & 15, b = i8 >> 20;
    if (t < 32){
        float v1 = statsP[h * 32 + t];
        float v2 = statsP[512 + h * 32 + t];
        #pragma unroll
        for (int off = 1; off < 32; off <<= 1){
            v1 += __shfl_xor(v1, off);
            v2 += __shfl_xor(v2, off);
        }
        if (t == 0){
            const float N = (float)(BB * LL * DD);
            float mean = v1 / N;
            float var  = fmaxf(v2 / N - mean * mean, 0.f);
            float a = ldx(bn_g, h, f32) * rsqrtf(var + 1e-5f);
            coefs[0] = a;
            coefs[1] = ldx(bn_b, h, f32) - mean * a;
        }
    }
    if (t < 64){
        int e = h * 64 + t;
        float S = 0.f;
        #pragma unroll
        for (int ch = 0; ch < 16; ++ch) S += Sp[(b * 16 + ch) * EE + e];
        sinv_s[t] = 1.f / S;
    }
    __syncthreads();
    const float bna = coefs[0], bnc = coefs[1];
    // ---- q path: BN + GELU in place on qbf
    {
        uint4 qr = *(const uint4*)(qbf + i8);
        unsigned short* qs = (unsigned short*)&qr;
        uint4 qw;
        unsigned short* qws = (unsigned short*)&qw;
        #pragma unroll
        for (int j = 0; j < 8; ++j){
            float x = bs2f(qs[j]) * bna + bnc;
            qws[j] = (unsigned short)f2bs(gelu_erf(x));
        }
        *(uint4*)(qbf + i8) = qw;
    }
    // ---- keys path -> kb2 tiled
    size_t kbase = ((size_t)b * LL + l) * EE + h * 64 + d0;
    float kv[8];
    if (f32){
        const float4* kp = (const float4*)((const float*)keys + kbase);
        float4 a = kp[0], c = kp[1];
        kv[0]=a.x; kv[1]=a.y; kv[2]=a.z; kv[3]=a.w;
        kv[4]=c.x; kv[5]=c.y; kv[6]=c.z; kv[7]=c.w;
    } else {
        uint4 kr = *(const uint4*)((const __hip_bfloat16*)keys + kbase);
        unsigned short* ks = (unsigned short*)&kr;
        #pragma unroll
        for (int j = 0; j < 8; ++j) kv[j] = bs2f(ks[j]);
    }
    float keep = berf[b * LL + l];
    uint4 kw;
    unsigned short* kws = (unsigned short*)&kw;
    #pragma unroll
    for (int j = 0; j < 8; ++j){
        float km = (keep != 0.f) ? kv[j] : NEGV;
        float p = __expf(km) * sinv_s[d0 + j];
        kws[j] = (unsigned short)f2bs(gelu_erf(p));
    }
    // tiled dest: rr=l&31 -> lid=((rr>>3)<<2)|(rr&3), nt2=(rr>>2)&1;
    // ck=d0>>5, quad=(d0>>3)&3; e spans 0..7 (d0 multiple of 8)
    {
        int bh = b * HH + h;
        int rr = l & 31;
        int lidK = ((rr >> 3) << 2) | (rr & 3);
        int nt2 = (rr >> 2) & 1;
        int ck = d0 >> 5, quad = (d0 >> 3) & 3;
        size_t dst = ((size_t)(bh * 32 + (l >> 5)) * 4 + nt2 * 2 + ck) * 512
                   + (quad * 16 + lidK) * 8;
        *(uint4*)(kb2 + dst) = kw;
    }
}

// ---------------------------------------------------------------------------
// kD: barrier-free MFMA flash attention, register-only P path, TRANS-free
// softmax, rotated K prefetch + early-V prefetch (R9 schedule, unchanged).
// R10: K/V loads read the TILED kb2/vb2 layouts -- each load instruction is
// one contiguous 1KB wave transaction (was a 16-row scatter; see layout
// comment above). Single experimental variable vs R9.
// 2048 blocks x 128 thr; 16 q-rows/block, waves split k 32/32; un-normalized
// additive softmax (LN over d is scale-invariant).
// ---------------------------------------------------------------------------
__global__ __launch_bounds__(128, 4) void kD(const __hip_bfloat16* __restrict__ qbf,
                                             const __hip_bfloat16* __restrict__ kb2,
                                             const __hip_bfloat16* __restrict__ vb2,
                                             const void* __restrict__ w_o,
                                             const void* __restrict__ b_o,
                                             const void* __restrict__ ln_g,
                                             const void* __restrict__ ln_b,
                                             const int* __restrict__ wsflag,
                                             void* __restrict__ out){
    __shared__ __align__(16) float Ol[16][68];              // wave-1 O for combine
    __shared__ __align__(16) __hip_bfloat16 onb[16][72];    // LN'd rows (A-frags)
    int blk = blockIdx.x;
    int qt = 63 - (blk >> 5);         // 16-row q tile; LPT (heavy first)
    int bh = blk & 31;                // b*16+h ; same-bh blocks share an XCD
    int h = bh & 15, b = bh >> 4;
    int t = threadIdx.x;
    int w = t >> 6, lane = t & 63;
    int lid = lane & 15, quad = lane >> 4;
    const int f32o = wsflag[0];

    // Q frags: already BN+GELU'd bf16 (kB) -- direct vector loads
    int qrow = qt * 16 + lid;
    bf16x8 qf[2];
    #pragma unroll
    for (int ck = 0; ck < 2; ++ck)
        qf[ck] = *(const bf16x8*)(qbf + ((size_t)bh * LL + qrow) * DD + ck * 32 + quad * 8);

    f32x4 O[4];
    #pragma unroll
    for (int nt = 0; nt < 4; ++nt) O[nt] = (f32x4){0.f, 0.f, 0.f, 0.f};
    const int qlane = qt * 16 + quad * 4;      // + r = this lane's OUTPUT q rows
    const int qcol  = qt * 16 + lid;           // this lane's q for S^T/P values
    const int nkt = (qt >> 2) + 1;             // 64-k tiles covering causal range

    bf16x8 kf[4], vf[4], vn[4];
    // tiled loads: one contiguous 1KB block per instruction
    auto loadK = [&](int kw){   // kw multiple of 32
        const __hip_bfloat16* base = kb2
            + ((size_t)(bh * 32 + (kw >> 5)) * 4) * 512 + lane * 8;
        #pragma unroll
        for (int i = 0; i < 4; ++i)
            kf[i] = *(const bf16x8*)(base + i * 512);
    };
    auto loadVf = [&](int kw){
        const __hip_bfloat16* base = vb2
            + ((size_t)(bh * 32 + (kw >> 5)) * 4) * 512 + lane * 8;
        #pragma unroll
        for (int nt = 0; nt < 4; ++nt)
            vf[nt] = *(const bf16x8*)(base + nt * 512);
    };
    auto loadVn = [&](int kw){
        const __hip_bfloat16* base = vb2
            + ((size_t)(bh * 32 + (kw >> 5)) * 4) * 512 + lane * 8;
        #pragma unroll
        for (int nt = 0; nt < 4; ++nt)
            vn[nt] = *(const bf16x8*)(base + nt * 512);
    };

    loadK(w * 32);
    loadVf(w * 32);

    for (int kt0 = 0; kt0 < nkt; ++kt0){
        int kw0 = kt0 * 64 + w * 32;
        const bool more = (kt0 + 1 < nkt);
        // S^T = K Q^T for this wave's 32k x 16q (2 x 16k chunks); consumes kf
        f32x4 S[2];
        __builtin_amdgcn_s_setprio(1);
        #pragma unroll
        for (int nt2 = 0; nt2 < 2; ++nt2){
            S[nt2] = (f32x4){0.f, 0.f, 0.f, 0.f};
            #pragma unroll
            for (int ck = 0; ck < 2; ++ck)
                S[nt2] = __builtin_amdgcn_mfma_f32_16x16x32_bf16(kf[nt2 * 2 + ck], qf[ck], S[nt2], 0, 0, 0);
        }
        __builtin_amdgcn_s_setprio(0);
        // rotate K prefetch (WAR after S consumed); issue next V into vn NOW
        if (more){
            loadK((kt0 + 1) * 64 + w * 32);
            loadVn((kt0 + 1) * 64 + w * 32);
        }
        // p = exp(poly_gelu(s)) causal-masked, packed to PV A-frag. TRANS-free.
        unsigned int pw0, pw1, pw2, pw3;
        {
            float ps[8];
            #pragma unroll
            for (int nt2 = 0; nt2 < 2; ++nt2)
                #pragma unroll
                for (int r = 0; r < 4; ++r){
                    int k = kw0 + quad * 8 + nt2 * 4 + r;
                    float x = gelu32_poly(S[nt2][r]);
                    float p = exp_valu(x);
                    ps[nt2 * 4 + r] = (k <= qcol) ? p : 0.f;
                }
            pw0 = pk2(ps[0], ps[1]); pw1 = pk2(ps[2], ps[3]);
            pw2 = pk2(ps[4], ps[5]); pw3 = pk2(ps[6], ps[7]);
        }
        union { unsigned int u[4]; bf16x8 v; } pu;
        pu.u[0] = pw0; pu.u[1] = pw1; pu.u[2] = pw2; pu.u[3] = pw3;
        bf16x8 pa = pu.v;
        // O += P V ; consumes vf
        __builtin_amdgcn_s_setprio(1);
        #pragma unroll
        for (int nt = 0; nt < 4; ++nt)
            O[nt] = __builtin_amdgcn_mfma_f32_16x16x32_bf16(pa, vf[nt], O[nt], 0, 0, 0);
        __builtin_amdgcn_s_setprio(0);
        if (more){
            #pragma unroll
            for (int nt = 0; nt < 4; ++nt) vf[nt] = vn[nt];
        }
    }

    // ---- combine the two k-half accumulators
    if (w == 1){
        #pragma unroll
        for (int nt = 0; nt < 4; ++nt)
            #pragma unroll
            for (int r = 0; r < 4; ++r)
                Ol[quad * 4 + r][nt * 16 + lid] = O[nt][r];
    }
    __syncthreads();
    if (w == 0){
        #pragma unroll
        for (int nt = 0; nt < 4; ++nt)
            #pragma unroll
            for (int r = 0; r < 4; ++r)
                O[nt][r] += Ol[quad * 4 + r][nt * 16 + lid];
        // LayerNorm over d (scale-invariant: unnormalized O is fine)
        float lng_v[4], lnb_v[4];
        #pragma unroll
        for (int nt = 0; nt < 4; ++nt){
            lng_v[nt] = ldx(ln_g, nt * 16 + lid, f32o);
            lnb_v[nt] = ldx(ln_b, nt * 16 + lid, f32o);
        }
        #pragma unroll
        for (int r = 0; r < 4; ++r){
            float s = O[0][r] + O[1][r] + O[2][r] + O[3][r];
            s = redsum16(s);
            float mu = s * (1.f / 64.f);
            float vs = 0.f;
            #pragma unroll
            for (int nt = 0; nt < 4; ++nt){ float d2 = O[nt][r] - mu; vs += d2 * d2; }
            vs = redsum16(vs);
            float iv = rsqrtf(vs * (1.f / 64.f) + 1e-5f);
            #pragma unroll
            for (int nt = 0; nt < 4; ++nt){
                float on = (O[nt][r] - mu) * iv * lng_v[nt] + lnb_v[nt];
                onb[quad * 4 + r][nt * 16 + lid] = __float2bfloat16(on);
            }
        }
    }
    __syncthreads();
    // ---- W_o epilogue, e-tiles split across waves (et = w*2 + i)
    bf16x8 oa0 = *(const bf16x8*)&onb[lid][quad * 8];
    bf16x8 oa1 = *(const bf16x8*)&onb[lid][32 + quad * 8];
    #pragma unroll
    for (int i = 0; i < 2; ++i){
        int et = w * 2 + i;
        float bo = ldx(b_o, et * 16 + lid, f32o);
        f32x4 R = (f32x4){bo, bo, bo, bo};
        bf16x8 bw0 = ld8b(w_o, (size_t)(et * 16 + lid) * 64 + quad * 8, f32o);
        bf16x8 bw1 = ld8b(w_o, (size_t)(et * 16 + lid) * 64 + 32 + quad * 8, f32o);
        R = __builtin_amdgcn_mfma_f32_16x16x32_bf16(oa0, bw0, R, 0, 0, 0);
        R = __builtin_amdgcn_mfma_f32_16x16x32_bf16(oa1, bw1, R, 0, 0, 0);
        #pragma unroll
        for (int r = 0; r < 4; ++r){
            size_t oidx = ((size_t)b * LL + qlane + r) * EE + h * 64 + et * 16 + lid;
            if (f32o) ((float*)out)[oidx] = R[r];
            else      ((__hip_bfloat16*)out)[oidx] = __float2bfloat16(R[r]);
        }
    }
}

// ---------------------------------------------------------------------------
extern "C" void kernel_launch(void* const* d_in, const int* in_sizes, int n_in,
                              void* d_out, int out_size, void* d_ws, size_t ws_size,
                              hipStream_t stream){
    int iq=-1, ik=-1, iv=-1, iber=-1, icw=-1, icb=-1, ibg=-1, ibb=-1,
        iwv=-1, ilg=-1, ilb=-1, iwo=-1, ibo=-1;
    int nbig=0, n16=0, n4096=0, n64=0;
    for (int i = 0; i < n_in; ++i){
        int s = in_sizes[i];
        if (s == BB*LL*EE){ if (nbig==0) iq=i; else if (nbig==1) ik=i; else if (nbig==2) iv=i; nbig++; }
        else if (s == BB*LL) iber = i;
        else if (s == HH*9)  icw = i;
        else if (s == HH){ if (n16==0) icb=i; else if (n16==1) ibg=i; else ibb=i; n16++; }
        else if (s == DD*DD){ if (n4096==0) iwv=i; else iwo=i; n4096++; }
        else if (s == DD){ if (n64==0) ilg=i; else if (n64==1) ilb=i; else ibo=i; n64++; }
    }
    if (iq<0||ik<0||iv<0||iber<0||icw<0||icb<0||ibg<0||ibb<0||iwv<0||ilg<0||ilb<0||iwo<0||ibo<0){
        iq=0; ik=1; iv=2; iber=5; icw=6; icb=7; ibg=8; ibb=9; iwv=10; ilg=11; ilb=12; iwo=13; ibo=14;
    }

    const size_t NEL = (size_t)BB * HH * LL * DD;   // 2M
    __hip_bfloat16* qbf = (__hip_bfloat16*)d_ws;    // 4 MB (conv out; kB applies BN+GELU in place)
    __hip_bfloat16* kb2 = qbf + NEL;                // 4 MB (tiled K)
    __hip_bfloat16* vb2 = kb2 + NEL;                // 4 MB (tiled V)
    float* f     = (float*)(vb2 + NEL);
    float* berf  = f;              // 2048
    float* statsP= f + 2048;       // 1024
    float* Sp    = f + 3072;       // 32768
    int*   wsflag= (int*)(f + 35840);  // 4

    hipLaunchKernelGGL(kA, dim3(1536), dim3(256), 0, stream,
                       d_in[iq], d_in[icw], d_in[icb], d_in[ik], d_in[iv], d_in[iwv],
                       (const unsigned char*)d_in[iber], statsP, Sp, berf, wsflag,
                       qbf, vb2);
    hipLaunchKernelGGL(kB, dim3(1024), dim3(256), 0, stream,
                       d_in[ik], d_in[ibg], d_in[ibb], statsP, Sp, berf, wsflag,
                       kb2, qbf);
    hipLaunchKernelGGL(kD, dim3(2048), dim3(128), 0, stream,
                       qbf, kb2, vb2, d_in[iwo], d_in[ibo], d_in[ilg], d_in[ilb],
                       wsflag, d_out);
}